// Round 12
// baseline (407.000 us; speedup 1.0000x reference)
//
#include <hip/hip_runtime.h>
#include <math.h>

#define NHEADS 6
#define CC 192
#define HDIM 32
#define NTOK 256
#define SHIFTV 8

typedef __attribute__((ext_vector_type(8))) short short8;   // 8 x bf16
typedef __attribute__((ext_vector_type(4))) short short4v;  // 4 x bf16
typedef __attribute__((ext_vector_type(4))) float floatx4;

#define LOG2E 1.4426950408889634f

__device__ inline short f2bf(float f) {
    union { float f; unsigned u; } v; v.f = f;
    unsigned r = (v.u + 0x7FFFu + ((v.u >> 16) & 1u)) >> 16;
    return (short)r;
}

// HW packed fp32->bf16 (RNE, same rounding as f2bf; 1 op for 2 elements vs 8).
__device__ inline unsigned cvt_pk_bf16(float a, float b) {
    unsigned r;
    asm("v_cvt_pk_bf16_f32 %0, %1, %2" : "=v"(r) : "v"(a), "v"(b));
    return r;
}

// tanh-form GELU as x*sigmoid(2u), u = 0.7978845608(x + 0.044715 x^3).
// |err| vs exact erf-GELU <= ~3e-3, below bf16 quantization of H.
__device__ inline float gelu_f(float x) {
    float x2 = x * x;
    float p = x * (-1.5957691216f - 0.07135481627f * x2);   // = -2u
    float e = __expf(p);
    return x * __builtin_amdgcn_rcpf(1.f + e);
}

// ---------------- weight convert/transpose to bf16 for MFMA B-fragments ----------------
// Row-major [n][k]. WQT 576x192, PWT 192x192, W1T 768x192, W2T 192x768
__global__ __launch_bounds__(256) void cvt_kernel(const float* __restrict__ qkvw,
                                                  const float* __restrict__ pw,
                                                  const float* __restrict__ f1w,
                                                  const float* __restrict__ f2w,
                                                  short* __restrict__ wqt,
                                                  short* __restrict__ pwt,
                                                  short* __restrict__ w1t,
                                                  short* __restrict__ w2t) {
    int idx = blockIdx.x * 256 + threadIdx.x;   // 147456 total
    int n = idx / 192, k = idx - n * 192;
    w1t[idx] = f2bf(f1w[k * 768 + n]);
    int c = idx / 768, h = idx - c * 768;
    w2t[idx] = f2bf(f2w[h * 192 + c]);
    if (idx < 576 * 192) wqt[idx] = f2bf(qkvw[k * 576 + n]);
    if (idx < 192 * 192) pwt[idx] = f2bf(pw[k * 192 + n]);
}

// ---------------- MFMA fused LN1 + shifted-window gather + QKV GEMM ----------------
// Q is pre-scaled by (1/sqrt(32)) * log2(e) so attn can use exp2 directly.
__global__ __launch_bounds__(256) void qkv_kernel(const float* __restrict__ x,
        const float* __restrict__ g1, const float* __restrict__ b1,
        const short* __restrict__ wqt, const float* __restrict__ qkvb,
        ushort* __restrict__ Qb, ushort* __restrict__ Kb, ushort* __restrict__ VTb) {
    __shared__ __align__(16) short xln[64 * 200];   // bf16 A-tile, stride 200
    __shared__ float red[64][4][2];
    const int t = threadIdx.x;
    const int g0 = blockIdx.x * 64;
    const int w = g0 >> 8;
    {
        int row = t >> 2, part = t & 3;
        int n = (g0 + row) & 255;
        int sy = (((w >> 4) << 4) + (n >> 4) + SHIFTV) & 255;
        int sx = (((w & 15) << 4) + (n & 15) + SHIFTV) & 255;
        const float* xr = x + (sy * 256 + sx) * CC + part * 48;
        float vals[48];
        float s = 0.f, ss = 0.f;
        #pragma unroll
        for (int i = 0; i < 48; ++i) { float v = xr[i]; vals[i] = v; s += v; ss += v * v; }
        red[row][part][0] = s; red[row][part][1] = ss;
        __syncthreads();
        float sum = red[row][0][0] + red[row][1][0] + red[row][2][0] + red[row][3][0];
        float sq  = red[row][0][1] + red[row][1][1] + red[row][2][1] + red[row][3][1];
        float mean = sum * (1.f / 192.f);
        float var = sq * (1.f / 192.f) - mean * mean;
        float inv = rsqrtf(var + 1e-5f);
        #pragma unroll
        for (int i = 0; i < 48; i += 2) {
            int c = part * 48 + i;
            float v0 = (vals[i] - mean) * inv * g1[c] + b1[c];
            float v1 = (vals[i + 1] - mean) * inv * g1[c + 1] + b1[c + 1];
            *(unsigned*)&xln[row * 200 + c] = cvt_pk_bf16(v0, v1);
        }
    }
    __syncthreads();
    const int wv = t >> 6, lane = t & 63;
    const int lr = lane & 15;
    const int lk = (lane >> 4) * 8;
    const int q4 = (lane >> 4) * 4;
    #pragma unroll
    for (int jc = 0; jc < 3; ++jc) {            // jc: 0=Q, 1=K, 2=V (192 cols each)
        floatx4 acc[4][3];
        #pragma unroll
        for (int mt = 0; mt < 4; ++mt)
            #pragma unroll
            for (int nt = 0; nt < 3; ++nt) acc[mt][nt] = floatx4{0.f,0.f,0.f,0.f};
        for (int ks = 0; ks < 6; ++ks) {
            int k0 = ks * 32 + lk;
            short8 a[4];
            #pragma unroll
            for (int mt = 0; mt < 4; ++mt)
                a[mt] = *(const short8*)&xln[(mt * 16 + lr) * 200 + k0];
            #pragma unroll
            for (int nt = 0; nt < 3; ++nt) {
                int nglob = jc * 192 + wv * 48 + nt * 16 + lr;
                short8 b = *(const short8*)&wqt[nglob * 192 + k0];
                #pragma unroll
                for (int mt = 0; mt < 4; ++mt)
                    acc[mt][nt] = __builtin_amdgcn_mfma_f32_16x16x32_bf16(a[mt], b, acc[mt][nt], 0, 0, 0);
            }
        }
        #pragma unroll
        for (int nt = 0; nt < 3; ++nt) {
            int jj = wv * 48 + nt * 16 + lr;      // 0..191 within section
            float bias = qkvb[jc * 192 + jj];
            int head = jj >> 5, hd = jj & 31;
            int wh = w * NHEADS + head;
            #pragma unroll
            for (int mt = 0; mt < 4; ++mt) {
                int nr0 = (g0 + mt * 16 + q4) & 255;
                if (jc == 0) {
                    #pragma unroll
                    for (int reg = 0; reg < 4; ++reg)
                        Qb[((size_t)wh * NTOK + nr0 + reg) * HDIM + hd] =
                            (ushort)f2bf((acc[mt][nt][reg] + bias) * (0.17677669529663687f * LOG2E));
                } else if (jc == 1) {
                    #pragma unroll
                    for (int reg = 0; reg < 4; ++reg)
                        Kb[((size_t)wh * NTOK + nr0 + reg) * HDIM + hd] =
                            (ushort)f2bf(acc[mt][nt][reg] + bias);
                } else {
                    uint2 pk;
                    pk.x = cvt_pk_bf16(acc[mt][nt][0] + bias, acc[mt][nt][1] + bias);
                    pk.y = cvt_pk_bf16(acc[mt][nt][2] + bias, acc[mt][nt][3] + bias);
                    *(uint2*)&VTb[((size_t)wh * HDIM + hd) * NTOK + nr0] = pk;
                }
            }
        }
    }
}

// ---------------- MFMA flash attention: analytic mask + analytic bias, NO K/V LDS staging ----------------
// Q and rpbh carry the log2(e) factor -> exp2f = bare v_exp_f32, no dependent
// v_mul between MFMA result and exp on the softmax critical chain.
__global__ __launch_bounds__(256) void attn_kernel(const ushort* __restrict__ Q,
        const ushort* __restrict__ K, const ushort* __restrict__ VT,
        const float* __restrict__ rpb,
        ushort* __restrict__ Ob) {
    __shared__ __align__(16) ushort Ps[4][64 * 40];  // per-wave P^T chunk [q][m], stride 40
    __shared__ float rpbh[961];                      // per-head bias, pre-scaled by log2e
    const int t = threadIdx.x;
    const int wh = blockIdx.x;
    const int w = wh / 6, h = wh - w * 6;
    const int wy = w >> 4, wx = w & 15;
    for (int i = t; i < 961; i += 256) rpbh[i] = rpb[i * 6 + h] * LOG2E;
    const int wv = t >> 6, lane = t & 63;
    const int lc = lane & 15;
    const int q4 = (lane >> 4) * 4;
    const int lk8 = (lane >> 4) * 8;
    const int qb = wv * 64;
    const bool cmask = (wx == 15) && ((lc >= 8) != (q4 >= 8));   // lane-constant
    const bool rowY  = (wy == 15);
    const int c0 = lc - q4 + 15;                                 // lane-constant bias column
    const ushort* kg = K + (size_t)wh * (NTOK * HDIM);
    const ushort* vg = VT + (size_t)wh * (NTOK * HDIM);
    short8 qf[4];
    {
        const ushort* qg = Q + (size_t)wh * (NTOK * HDIM);
        #pragma unroll
        for (int qt = 0; qt < 4; ++qt)
            qf[qt] = *(const short8*)(qg + (qb + qt * 16 + lc) * HDIM + lk8);
    }
    __syncthreads();   // rpbh visible
    float Ssum[4];
    floatx4 o[2][4];
    #pragma unroll
    for (int qt = 0; qt < 4; ++qt) {
        Ssum[qt] = 0.f;
        o[0][qt] = floatx4{0.f,0.f,0.f,0.f};
        o[1][qt] = floatx4{0.f,0.f,0.f,0.f};
    }
    ushort* Pw = &Ps[wv][0];
    for (int kc = 0; kc < 8; ++kc) {
        const int k0 = kc * 32;
        short8 ka[2];
        ka[0] = *(const short8*)(kg + (k0 + lc) * HDIM + lk8);
        ka[1] = *(const short8*)(kg + (k0 + 16 + lc) * HDIM + lk8);
        floatx4 sf[2][4];
        #pragma unroll
        for (int kt = 0; kt < 2; ++kt)
            #pragma unroll
            for (int qt = 0; qt < 4; ++qt)
                sf[kt][qt] = __builtin_amdgcn_mfma_f32_16x16x32_bf16(ka[kt], qf[qt],
                                floatx4{0.f,0.f,0.f,0.f}, 0, 0, 0);
        #pragma unroll
        for (int kt = 0; kt < 2; ++kt)
            #pragma unroll
            for (int qt = 0; qt < 4; ++qt) {
                bool msk = cmask || (rowY && (((wv * 4 + qt) >= 8) != ((kc * 2 + kt) >= 8)));
                const float* rb = &rpbh[((wv * 4 + qt) - (kc * 2 + kt) + 15) * 31 + c0];
                float p0 = msk ? 0.f : exp2f(sf[kt][qt][0] + rb[0]);
                float p1 = msk ? 0.f : exp2f(sf[kt][qt][1] + rb[-1]);
                float p2 = msk ? 0.f : exp2f(sf[kt][qt][2] + rb[-2]);
                float p3 = msk ? 0.f : exp2f(sf[kt][qt][3] + rb[-3]);
                Ssum[qt] += (p0 + p1) + (p2 + p3);
                uint2 pk;
                pk.x = cvt_pk_bf16(p0, p1);
                pk.y = cvt_pk_bf16(p2, p3);
                *(uint2*)&Pw[(qt * 16 + lc) * 40 + kt * 16 + q4] = pk;
            }
        short8 va[2], pf[4];
        va[0] = *(const short8*)(vg + lc * NTOK + k0 + lk8);
        va[1] = *(const short8*)(vg + (16 + lc) * NTOK + k0 + lk8);
        #pragma unroll
        for (int qt = 0; qt < 4; ++qt)
            pf[qt] = *(const short8*)&Pw[(qt * 16 + lc) * 40 + lk8];
        #pragma unroll
        for (int ht = 0; ht < 2; ++ht)
            #pragma unroll
            for (int qt = 0; qt < 4; ++qt)
                o[ht][qt] = __builtin_amdgcn_mfma_f32_16x16x32_bf16(va[ht], pf[qt], o[ht][qt], 0, 0, 0);
    }
    #pragma unroll
    for (int qt = 0; qt < 4; ++qt) {
        float rs = Ssum[qt];
        rs += __shfl_xor(rs, 16);
        rs += __shfl_xor(rs, 32);
        float inv = 1.f / rs;
        size_t rowbase = ((size_t)(w * NTOK + qb + qt * 16 + lc)) * CC + h * HDIM;
        #pragma unroll
        for (int ht = 0; ht < 2; ++ht) {
            uint2 pk;
            pk.x = cvt_pk_bf16(o[ht][qt][0] * inv, o[ht][qt][1] * inv);
            pk.y = cvt_pk_bf16(o[ht][qt][2] * inv, o[ht][qt][3] * inv);
            *(uint2*)&Ob[rowbase + ht * 16 + q4] = pk;
        }
    }
}

// ---------------- MFMA proj GEMM + window reverse/unshift + residual(x) ----------------
__global__ __launch_bounds__(256) void proj_kernel(const ushort* __restrict__ Ob,
        const short* __restrict__ pwt, const float* __restrict__ pb,
        const float* __restrict__ x, float* __restrict__ out) {
    __shared__ __align__(16) short oln[64 * 200];
    const int t = threadIdx.x;
    const int g0 = blockIdx.x * 64;
    const int w = g0 >> 8;
    {
        int row = t >> 2, part = t & 3;
        const ushort* orow = Ob + (size_t)(g0 + row) * CC + part * 48;
        #pragma unroll
        for (int i = 0; i < 6; ++i)
            *(short8*)&oln[row * 200 + part * 48 + i * 8] = *(const short8*)(orow + i * 8);
    }
    __syncthreads();
    const int wv = t >> 6, lane = t & 63;
    const int lr = lane & 15;
    const int lk = (lane >> 4) * 8;
    const int q4 = (lane >> 4) * 4;
    floatx4 acc[4][3];
    #pragma unroll
    for (int mt = 0; mt < 4; ++mt)
        #pragma unroll
        for (int nt = 0; nt < 3; ++nt) acc[mt][nt] = floatx4{0.f,0.f,0.f,0.f};
    for (int ks = 0; ks < 6; ++ks) {
        int k0 = ks * 32 + lk;
        short8 a[4];
        #pragma unroll
        for (int mt = 0; mt < 4; ++mt)
            a[mt] = *(const short8*)&oln[(mt * 16 + lr) * 200 + k0];
        #pragma unroll
        for (int nt = 0; nt < 3; ++nt) {
            int c = wv * 48 + nt * 16 + lr;
            short8 b = *(const short8*)&pwt[c * 192 + k0];
            #pragma unroll
            for (int mt = 0; mt < 4; ++mt)
                acc[mt][nt] = __builtin_amdgcn_mfma_f32_16x16x32_bf16(a[mt], b, acc[mt][nt], 0, 0, 0);
        }
    }
    #pragma unroll
    for (int nt = 0; nt < 3; ++nt) {
        int c = wv * 48 + nt * 16 + lr;
        float bias = pb[c];
        #pragma unroll
        for (int mt = 0; mt < 4; ++mt) {
            #pragma unroll
            for (int reg = 0; reg < 4; ++reg) {
                int nn = (g0 + mt * 16 + q4 + reg) & 255;
                int sy = (((w >> 4) << 4) + (nn >> 4) + SHIFTV) & 255;
                int sx = (((w & 15) << 4) + (nn & 15) + SHIFTV) & 255;
                size_t base = (size_t)(sy * 256 + sx) * CC;
                out[base + c] = x[base + c] + acc[mt][nt][reg] + bias;
            }
        }
    }
}

// ---------------- MFMA MLP (R7 proven): LN2 + fc1 + fast GELU + fc2 + residual ----------------
// 64-token tile, 4 hidden chunks of 192, 8 barriers. Structurally settled.
__global__ __launch_bounds__(256) void mlp_kernel(const float* __restrict__ g2,
        const float* __restrict__ b2, const short* __restrict__ w1t,
        const float* __restrict__ f1b, const short* __restrict__ w2t,
        const float* __restrict__ f2b, float* __restrict__ out) {
    __shared__ __align__(16) short xln[64 * 200];
    __shared__ __align__(16) short Hs[64 * 200];
    __shared__ float red[64][4][2];
    const int t = threadIdx.x;
    const int m0 = blockIdx.x * 64;
    {
        int row = t >> 2, part = t & 3;
        const float* xr = out + (size_t)(m0 + row) * CC + part * 48;
        float vals[48];
        float s = 0.f, ss = 0.f;
        #pragma unroll
        for (int i = 0; i < 48; ++i) { float v = xr[i]; vals[i] = v; s += v; ss += v * v; }
        red[row][part][0] = s; red[row][part][1] = ss;
        __syncthreads();
        float sum = red[row][0][0] + red[row][1][0] + red[row][2][0] + red[row][3][0];
        float sq  = red[row][0][1] + red[row][1][1] + red[row][2][1] + red[row][3][1];
        float mean = sum * (1.f / 192.f);
        float var = sq * (1.f / 192.f) - mean * mean;
        float inv = rsqrtf(var + 1e-5f);
        #pragma unroll
        for (int i = 0; i < 48; i += 2) {
            int c = part * 48 + i;
            float v0 = (vals[i] - mean) * inv * g2[c] + b2[c];
            float v1 = (vals[i + 1] - mean) * inv * g2[c + 1] + b2[c + 1];
            *(unsigned*)&xln[row * 200 + c] = cvt_pk_bf16(v0, v1);
        }
    }
    __syncthreads();
    const int wv = t >> 6;
    const int lane = t & 63;
    const int lr = lane & 15;
    const int lk = (lane >> 4) * 8;
    const int q4 = (lane >> 4) * 4;
    floatx4 acc2[4][3];
    #pragma unroll
    for (int mt = 0; mt < 4; ++mt)
        #pragma unroll
        for (int nt = 0; nt < 3; ++nt) acc2[mt][nt] = floatx4{0.f, 0.f, 0.f, 0.f};

    for (int hc = 0; hc < 4; ++hc) {
        // ---- fc1: 64 x 192 chunk; wave owns cols [wv*48, wv*48+48) ----
        floatx4 acc1[4][3];
        #pragma unroll
        for (int mt = 0; mt < 4; ++mt)
            #pragma unroll
            for (int nt = 0; nt < 3; ++nt) acc1[mt][nt] = floatx4{0.f, 0.f, 0.f, 0.f};
        for (int ks = 0; ks < 6; ++ks) {
            int k0 = ks * 32 + lk;
            short8 a[4];
            #pragma unroll
            for (int mt = 0; mt < 4; ++mt)
                a[mt] = *(const short8*)&xln[(mt * 16 + lr) * 200 + k0];
            #pragma unroll
            for (int nt = 0; nt < 3; ++nt) {
                int n = hc * 192 + wv * 48 + nt * 16 + lr;
                short8 b = *(const short8*)&w1t[n * 192 + k0];
                #pragma unroll
                for (int mt = 0; mt < 4; ++mt)
                    acc1[mt][nt] = __builtin_amdgcn_mfma_f32_16x16x32_bf16(a[mt], b, acc1[mt][nt], 0, 0, 0);
            }
        }
        __syncthreads();   // prior fc2 reads of Hs complete (WAR)
        #pragma unroll
        for (int nt = 0; nt < 3; ++nt) {
            int colb = wv * 48 + nt * 16 + lr;           // 0..191 within chunk
            float bias = f1b[hc * 192 + colb];
            #pragma unroll
            for (int mt = 0; mt < 4; ++mt) {
                #pragma unroll
                for (int reg = 0; reg < 4; ++reg) {
                    float v = acc1[mt][nt][reg] + bias;
                    Hs[(mt * 16 + q4 + reg) * 200 + colb] = f2bf(gelu_f(v));
                }
            }
        }
        __syncthreads();   // Hs visible to all waves (RAW)
        // ---- fc2 accumulate over this chunk's 192 hiddens ----
        for (int ks = 0; ks < 6; ++ks) {
            int k0 = ks * 32 + lk;
            short8 a[4];
            #pragma unroll
            for (int mt = 0; mt < 4; ++mt)
                a[mt] = *(const short8*)&Hs[(mt * 16 + lr) * 200 + k0];
            #pragma unroll
            for (int nt = 0; nt < 3; ++nt) {
                int c = wv * 48 + nt * 16 + lr;
                short8 b = *(const short8*)&w2t[c * 768 + hc * 192 + k0];
                #pragma unroll
                for (int mt = 0; mt < 4; ++mt)
                    acc2[mt][nt] = __builtin_amdgcn_mfma_f32_16x16x32_bf16(a[mt], b, acc2[mt][nt], 0, 0, 0);
            }
        }
    }
    #pragma unroll
    for (int nt = 0; nt < 3; ++nt) {
        int c = wv * 48 + nt * 16 + lr;
        float bias = f2b[c];
        #pragma unroll
        for (int mt = 0; mt < 4; ++mt) {
            #pragma unroll
            for (int reg = 0; reg < 4; ++reg) {
                size_t off = (size_t)(m0 + mt * 16 + q4 + reg) * CC + c;
                out[off] = out[off] + acc2[mt][nt][reg] + bias;
            }
        }
    }
}

extern "C" void kernel_launch(void* const* d_in, const int* in_sizes, int n_in,
                              void* d_out, int out_size, void* d_ws, size_t ws_size,
                              hipStream_t stream) {
    (void)in_sizes; (void)n_in; (void)out_size; (void)ws_size;
    const float* x    = (const float*)d_in[0];
    const float* n1g  = (const float*)d_in[3];
    const float* n1b  = (const float*)d_in[4];
    const float* qkvw = (const float*)d_in[5];
    const float* qkvb = (const float*)d_in[6];
    const float* rpb  = (const float*)d_in[7];
    const float* pw   = (const float*)d_in[8];
    const float* pb   = (const float*)d_in[9];
    const float* n2g  = (const float*)d_in[10];
    const float* n2b  = (const float*)d_in[11];
    const float* f1w  = (const float*)d_in[12];
    const float* f1b  = (const float*)d_in[13];
    const float* f2w  = (const float*)d_in[14];
    const float* f2b  = (const float*)d_in[15];
    float* out = (float*)d_out;

    ushort* Qb  = (ushort*)d_ws;            // 12,582,912 bf16 each
    ushort* Kb  = Qb + 12582912;
    ushort* VTb = Kb + 12582912;
    ushort* Ob  = VTb + 12582912;
    short* WQT  = (short*)(Ob + 12582912);  // 110,592 bf16
    short* PWT  = WQT + 110592;             // 36,864 bf16
    short* W1T  = PWT + 36864;              // 147,456 bf16
    short* W2T  = W1T + 147456;             // 147,456 bf16

    cvt_kernel<<<576, 256, 0, stream>>>(qkvw, pw, f1w, f2w, WQT, PWT, W1T, W2T);
    qkv_kernel<<<1024, 256, 0, stream>>>(x, n1g, n1b, WQT, qkvb, Qb, Kb, VTb);
    attn_kernel<<<1536, 256, 0, stream>>>(Qb, Kb, VTb, rpb, Ob);
    proj_kernel<<<1024, 256, 0, stream>>>(Ob, PWT, pb, x, out);
    mlp_kernel<<<1024, 256, 0, stream>>>(n2g, n2b, W1T, f1b, W2T, f2b, out);
}

// Round 13
// 398.054 us; speedup vs baseline: 1.0225x; 1.0225x over previous
//
#include <hip/hip_runtime.h>
#include <math.h>

#define NHEADS 6
#define CC 192
#define HDIM 32
#define NTOK 256
#define SHIFTV 8

typedef __attribute__((ext_vector_type(8))) short short8;   // 8 x bf16
typedef __attribute__((ext_vector_type(4))) short short4v;  // 4 x bf16
typedef __attribute__((ext_vector_type(4))) float floatx4;

#define LOG2E 1.4426950408889634f

__device__ inline short f2bf(float f) {
    union { float f; unsigned u; } v; v.f = f;
    unsigned r = (v.u + 0x7FFFu + ((v.u >> 16) & 1u)) >> 16;
    return (short)r;
}

// HW packed fp32->bf16 (RNE, same rounding as f2bf; 1 op for 2 elements vs 8).
__device__ inline unsigned cvt_pk_bf16(float a, float b) {
    unsigned r;
    asm("v_cvt_pk_bf16_f32 %0, %1, %2" : "=v"(r) : "v"(a), "v"(b));
    return r;
}

// tanh-form GELU as x*sigmoid(2u), u = 0.7978845608(x + 0.044715 x^3).
// |err| vs exact erf-GELU <= ~3e-3, below bf16 quantization of H.
__device__ inline float gelu_f(float x) {
    float x2 = x * x;
    float p = x * (-1.5957691216f - 0.07135481627f * x2);   // = -2u
    float e = __expf(p);
    return x * __builtin_amdgcn_rcpf(1.f + e);
}

// ---------------- weight convert/transpose to bf16 for MFMA B-fragments ----------------
// Row-major [n][k]. WQT 576x192, PWT 192x192, W1T 768x192, W2T 192x768
__global__ __launch_bounds__(256) void cvt_kernel(const float* __restrict__ qkvw,
                                                  const float* __restrict__ pw,
                                                  const float* __restrict__ f1w,
                                                  const float* __restrict__ f2w,
                                                  short* __restrict__ wqt,
                                                  short* __restrict__ pwt,
                                                  short* __restrict__ w1t,
                                                  short* __restrict__ w2t) {
    int idx = blockIdx.x * 256 + threadIdx.x;   // 147456 total
    int n = idx / 192, k = idx - n * 192;
    w1t[idx] = f2bf(f1w[k * 768 + n]);
    int c = idx / 768, h = idx - c * 768;
    w2t[idx] = f2bf(f2w[h * 192 + c]);
    if (idx < 576 * 192) wqt[idx] = f2bf(qkvw[k * 576 + n]);
    if (idx < 192 * 192) pwt[idx] = f2bf(pw[k * 192 + n]);
}

// ---------------- MFMA fused LN1 + shifted-window gather + QKV GEMM ----------------
// Q is pre-scaled by (1/sqrt(32)) * log2(e) so attn can use exp2 directly.
__global__ __launch_bounds__(256) void qkv_kernel(const float* __restrict__ x,
        const float* __restrict__ g1, const float* __restrict__ b1,
        const short* __restrict__ wqt, const float* __restrict__ qkvb,
        ushort* __restrict__ Qb, ushort* __restrict__ Kb, ushort* __restrict__ VTb) {
    __shared__ __align__(16) short xln[64 * 200];   // bf16 A-tile, stride 200
    __shared__ float red[64][4][2];
    const int t = threadIdx.x;
    const int g0 = blockIdx.x * 64;
    const int w = g0 >> 8;
    {
        int row = t >> 2, part = t & 3;
        int n = (g0 + row) & 255;
        int sy = (((w >> 4) << 4) + (n >> 4) + SHIFTV) & 255;
        int sx = (((w & 15) << 4) + (n & 15) + SHIFTV) & 255;
        const float* xr = x + (sy * 256 + sx) * CC + part * 48;
        float vals[48];
        float s = 0.f, ss = 0.f;
        #pragma unroll
        for (int i = 0; i < 48; ++i) { float v = xr[i]; vals[i] = v; s += v; ss += v * v; }
        red[row][part][0] = s; red[row][part][1] = ss;
        __syncthreads();
        float sum = red[row][0][0] + red[row][1][0] + red[row][2][0] + red[row][3][0];
        float sq  = red[row][0][1] + red[row][1][1] + red[row][2][1] + red[row][3][1];
        float mean = sum * (1.f / 192.f);
        float var = sq * (1.f / 192.f) - mean * mean;
        float inv = rsqrtf(var + 1e-5f);
        #pragma unroll
        for (int i = 0; i < 48; i += 2) {
            int c = part * 48 + i;
            float v0 = (vals[i] - mean) * inv * g1[c] + b1[c];
            float v1 = (vals[i + 1] - mean) * inv * g1[c + 1] + b1[c + 1];
            *(unsigned*)&xln[row * 200 + c] = cvt_pk_bf16(v0, v1);
        }
    }
    __syncthreads();
    const int wv = t >> 6, lane = t & 63;
    const int lr = lane & 15;
    const int lk = (lane >> 4) * 8;
    const int q4 = (lane >> 4) * 4;
    #pragma unroll
    for (int jc = 0; jc < 3; ++jc) {            // jc: 0=Q, 1=K, 2=V (192 cols each)
        floatx4 acc[4][3];
        #pragma unroll
        for (int mt = 0; mt < 4; ++mt)
            #pragma unroll
            for (int nt = 0; nt < 3; ++nt) acc[mt][nt] = floatx4{0.f,0.f,0.f,0.f};
        for (int ks = 0; ks < 6; ++ks) {
            int k0 = ks * 32 + lk;
            short8 a[4];
            #pragma unroll
            for (int mt = 0; mt < 4; ++mt)
                a[mt] = *(const short8*)&xln[(mt * 16 + lr) * 200 + k0];
            #pragma unroll
            for (int nt = 0; nt < 3; ++nt) {
                int nglob = jc * 192 + wv * 48 + nt * 16 + lr;
                short8 b = *(const short8*)&wqt[nglob * 192 + k0];
                #pragma unroll
                for (int mt = 0; mt < 4; ++mt)
                    acc[mt][nt] = __builtin_amdgcn_mfma_f32_16x16x32_bf16(a[mt], b, acc[mt][nt], 0, 0, 0);
            }
        }
        #pragma unroll
        for (int nt = 0; nt < 3; ++nt) {
            int jj = wv * 48 + nt * 16 + lr;      // 0..191 within section
            float bias = qkvb[jc * 192 + jj];
            int head = jj >> 5, hd = jj & 31;
            int wh = w * NHEADS + head;
            #pragma unroll
            for (int mt = 0; mt < 4; ++mt) {
                int nr0 = (g0 + mt * 16 + q4) & 255;
                if (jc == 0) {
                    #pragma unroll
                    for (int reg = 0; reg < 4; ++reg)
                        Qb[((size_t)wh * NTOK + nr0 + reg) * HDIM + hd] =
                            (ushort)f2bf((acc[mt][nt][reg] + bias) * (0.17677669529663687f * LOG2E));
                } else if (jc == 1) {
                    #pragma unroll
                    for (int reg = 0; reg < 4; ++reg)
                        Kb[((size_t)wh * NTOK + nr0 + reg) * HDIM + hd] =
                            (ushort)f2bf(acc[mt][nt][reg] + bias);
                } else {
                    uint2 pk;
                    pk.x = cvt_pk_bf16(acc[mt][nt][0] + bias, acc[mt][nt][1] + bias);
                    pk.y = cvt_pk_bf16(acc[mt][nt][2] + bias, acc[mt][nt][3] + bias);
                    *(uint2*)&VTb[((size_t)wh * HDIM + hd) * NTOK + nr0] = pk;
                }
            }
        }
    }
}

// ---------------- MFMA flash attention: analytic mask + analytic bias, NO K/V LDS staging ----------------
// Q and rpbh carry the log2(e) factor -> exp2f = bare v_exp_f32.
__global__ __launch_bounds__(256) void attn_kernel(const ushort* __restrict__ Q,
        const ushort* __restrict__ K, const ushort* __restrict__ VT,
        const float* __restrict__ rpb,
        ushort* __restrict__ Ob) {
    __shared__ __align__(16) ushort Ps[4][64 * 40];  // per-wave P^T chunk [q][m], stride 40
    __shared__ float rpbh[961];                      // per-head bias, pre-scaled by log2e
    const int t = threadIdx.x;
    const int wh = blockIdx.x;
    const int w = wh / 6, h = wh - w * 6;
    const int wy = w >> 4, wx = w & 15;
    for (int i = t; i < 961; i += 256) rpbh[i] = rpb[i * 6 + h] * LOG2E;
    const int wv = t >> 6, lane = t & 63;
    const int lc = lane & 15;
    const int q4 = (lane >> 4) * 4;
    const int lk8 = (lane >> 4) * 8;
    const int qb = wv * 64;
    const bool cmask = (wx == 15) && ((lc >= 8) != (q4 >= 8));   // lane-constant
    const bool rowY  = (wy == 15);
    const int c0 = lc - q4 + 15;                                 // lane-constant bias column
    const ushort* kg = K + (size_t)wh * (NTOK * HDIM);
    const ushort* vg = VT + (size_t)wh * (NTOK * HDIM);
    short8 qf[4];
    {
        const ushort* qg = Q + (size_t)wh * (NTOK * HDIM);
        #pragma unroll
        for (int qt = 0; qt < 4; ++qt)
            qf[qt] = *(const short8*)(qg + (qb + qt * 16 + lc) * HDIM + lk8);
    }
    __syncthreads();   // rpbh visible
    float Ssum[4];
    floatx4 o[2][4];
    #pragma unroll
    for (int qt = 0; qt < 4; ++qt) {
        Ssum[qt] = 0.f;
        o[0][qt] = floatx4{0.f,0.f,0.f,0.f};
        o[1][qt] = floatx4{0.f,0.f,0.f,0.f};
    }
    ushort* Pw = &Ps[wv][0];
    for (int kc = 0; kc < 8; ++kc) {
        const int k0 = kc * 32;
        short8 ka[2];
        ka[0] = *(const short8*)(kg + (k0 + lc) * HDIM + lk8);
        ka[1] = *(const short8*)(kg + (k0 + 16 + lc) * HDIM + lk8);
        floatx4 sf[2][4];
        #pragma unroll
        for (int kt = 0; kt < 2; ++kt)
            #pragma unroll
            for (int qt = 0; qt < 4; ++qt)
                sf[kt][qt] = __builtin_amdgcn_mfma_f32_16x16x32_bf16(ka[kt], qf[qt],
                                floatx4{0.f,0.f,0.f,0.f}, 0, 0, 0);
        #pragma unroll
        for (int kt = 0; kt < 2; ++kt)
            #pragma unroll
            for (int qt = 0; qt < 4; ++qt) {
                bool msk = cmask || (rowY && (((wv * 4 + qt) >= 8) != ((kc * 2 + kt) >= 8)));
                const float* rb = &rpbh[((wv * 4 + qt) - (kc * 2 + kt) + 15) * 31 + c0];
                float p0 = msk ? 0.f : exp2f(sf[kt][qt][0] + rb[0]);
                float p1 = msk ? 0.f : exp2f(sf[kt][qt][1] + rb[-1]);
                float p2 = msk ? 0.f : exp2f(sf[kt][qt][2] + rb[-2]);
                float p3 = msk ? 0.f : exp2f(sf[kt][qt][3] + rb[-3]);
                Ssum[qt] += (p0 + p1) + (p2 + p3);
                uint2 pk;
                pk.x = cvt_pk_bf16(p0, p1);
                pk.y = cvt_pk_bf16(p2, p3);
                *(uint2*)&Pw[(qt * 16 + lc) * 40 + kt * 16 + q4] = pk;
            }
        short8 va[2], pf[4];
        va[0] = *(const short8*)(vg + lc * NTOK + k0 + lk8);
        va[1] = *(const short8*)(vg + (16 + lc) * NTOK + k0 + lk8);
        #pragma unroll
        for (int qt = 0; qt < 4; ++qt)
            pf[qt] = *(const short8*)&Pw[(qt * 16 + lc) * 40 + lk8];
        #pragma unroll
        for (int ht = 0; ht < 2; ++ht)
            #pragma unroll
            for (int qt = 0; qt < 4; ++qt)
                o[ht][qt] = __builtin_amdgcn_mfma_f32_16x16x32_bf16(va[ht], pf[qt], o[ht][qt], 0, 0, 0);
    }
    #pragma unroll
    for (int qt = 0; qt < 4; ++qt) {
        float rs = Ssum[qt];
        rs += __shfl_xor(rs, 16);
        rs += __shfl_xor(rs, 32);
        float inv = 1.f / rs;
        size_t rowbase = ((size_t)(w * NTOK + qb + qt * 16 + lc)) * CC + h * HDIM;
        #pragma unroll
        for (int ht = 0; ht < 2; ++ht) {
            uint2 pk;
            pk.x = cvt_pk_bf16(o[ht][qt][0] * inv, o[ht][qt][1] * inv);
            pk.y = cvt_pk_bf16(o[ht][qt][2] * inv, o[ht][qt][3] * inv);
            *(uint2*)&Ob[rowbase + ht * 16 + q4] = pk;
        }
    }
}

// ---------------- MFMA proj GEMM + window reverse/unshift + residual(x) ----------------
// De-staged (R7 mechanism): Ob tile (24KB) is L2-hot (just written by attn) and
// read only once per wave -> direct global A-fragment reads, no LDS, no staging
// barrier. Same per-wave access shape as attn's proven direct K loads.
__global__ __launch_bounds__(256) void proj_kernel(const ushort* __restrict__ Ob,
        const short* __restrict__ pwt, const float* __restrict__ pb,
        const float* __restrict__ x, float* __restrict__ out) {
    const int t = threadIdx.x;
    const int g0 = blockIdx.x * 64;
    const int w = g0 >> 8;
    const int wv = t >> 6, lane = t & 63;
    const int lr = lane & 15;
    const int lk = (lane >> 4) * 8;
    const int q4 = (lane >> 4) * 4;
    const ushort* og = Ob + (size_t)g0 * CC;
    floatx4 acc[4][3];
    #pragma unroll
    for (int mt = 0; mt < 4; ++mt)
        #pragma unroll
        for (int nt = 0; nt < 3; ++nt) acc[mt][nt] = floatx4{0.f,0.f,0.f,0.f};
    for (int ks = 0; ks < 6; ++ks) {
        int k0 = ks * 32 + lk;
        short8 a[4];
        #pragma unroll
        for (int mt = 0; mt < 4; ++mt)
            a[mt] = *(const short8*)(og + (mt * 16 + lr) * CC + k0);
        #pragma unroll
        for (int nt = 0; nt < 3; ++nt) {
            int c = wv * 48 + nt * 16 + lr;
            short8 b = *(const short8*)&pwt[c * 192 + k0];
            #pragma unroll
            for (int mt = 0; mt < 4; ++mt)
                acc[mt][nt] = __builtin_amdgcn_mfma_f32_16x16x32_bf16(a[mt], b, acc[mt][nt], 0, 0, 0);
        }
    }
    #pragma unroll
    for (int nt = 0; nt < 3; ++nt) {
        int c = wv * 48 + nt * 16 + lr;
        float bias = pb[c];
        #pragma unroll
        for (int mt = 0; mt < 4; ++mt) {
            #pragma unroll
            for (int reg = 0; reg < 4; ++reg) {
                int nn = (g0 + mt * 16 + q4 + reg) & 255;
                int sy = (((w >> 4) << 4) + (nn >> 4) + SHIFTV) & 255;
                int sx = (((w & 15) << 4) + (nn & 15) + SHIFTV) & 255;
                size_t base = (size_t)(sy * 256 + sx) * CC;
                out[base + c] = x[base + c] + acc[mt][nt][reg] + bias;
            }
        }
    }
}

// ---------------- MFMA MLP (R7 proven): LN2 + fc1 + fast GELU + fc2 + residual ----------------
// 64-token tile, 4 hidden chunks of 192, 8 barriers. Structurally settled.
__global__ __launch_bounds__(256) void mlp_kernel(const float* __restrict__ g2,
        const float* __restrict__ b2, const short* __restrict__ w1t,
        const float* __restrict__ f1b, const short* __restrict__ w2t,
        const float* __restrict__ f2b, float* __restrict__ out) {
    __shared__ __align__(16) short xln[64 * 200];
    __shared__ __align__(16) short Hs[64 * 200];
    __shared__ float red[64][4][2];
    const int t = threadIdx.x;
    const int m0 = blockIdx.x * 64;
    {
        int row = t >> 2, part = t & 3;
        const float* xr = out + (size_t)(m0 + row) * CC + part * 48;
        float vals[48];
        float s = 0.f, ss = 0.f;
        #pragma unroll
        for (int i = 0; i < 48; ++i) { float v = xr[i]; vals[i] = v; s += v; ss += v * v; }
        red[row][part][0] = s; red[row][part][1] = ss;
        __syncthreads();
        float sum = red[row][0][0] + red[row][1][0] + red[row][2][0] + red[row][3][0];
        float sq  = red[row][0][1] + red[row][1][1] + red[row][2][1] + red[row][3][1];
        float mean = sum * (1.f / 192.f);
        float var = sq * (1.f / 192.f) - mean * mean;
        float inv = rsqrtf(var + 1e-5f);
        #pragma unroll
        for (int i = 0; i < 48; i += 2) {
            int c = part * 48 + i;
            float v0 = (vals[i] - mean) * inv * g2[c] + b2[c];
            float v1 = (vals[i + 1] - mean) * inv * g2[c + 1] + b2[c + 1];
            *(unsigned*)&xln[row * 200 + c] = cvt_pk_bf16(v0, v1);
        }
    }
    __syncthreads();
    const int wv = t >> 6;
    const int lane = t & 63;
    const int lr = lane & 15;
    const int lk = (lane >> 4) * 8;
    const int q4 = (lane >> 4) * 4;
    floatx4 acc2[4][3];
    #pragma unroll
    for (int mt = 0; mt < 4; ++mt)
        #pragma unroll
        for (int nt = 0; nt < 3; ++nt) acc2[mt][nt] = floatx4{0.f, 0.f, 0.f, 0.f};

    for (int hc = 0; hc < 4; ++hc) {
        // ---- fc1: 64 x 192 chunk; wave owns cols [wv*48, wv*48+48) ----
        floatx4 acc1[4][3];
        #pragma unroll
        for (int mt = 0; mt < 4; ++mt)
            #pragma unroll
            for (int nt = 0; nt < 3; ++nt) acc1[mt][nt] = floatx4{0.f, 0.f, 0.f, 0.f};
        for (int ks = 0; ks < 6; ++ks) {
            int k0 = ks * 32 + lk;
            short8 a[4];
            #pragma unroll
            for (int mt = 0; mt < 4; ++mt)
                a[mt] = *(const short8*)&xln[(mt * 16 + lr) * 200 + k0];
            #pragma unroll
            for (int nt = 0; nt < 3; ++nt) {
                int n = hc * 192 + wv * 48 + nt * 16 + lr;
                short8 b = *(const short8*)&w1t[n * 192 + k0];
                #pragma unroll
                for (int mt = 0; mt < 4; ++mt)
                    acc1[mt][nt] = __builtin_amdgcn_mfma_f32_16x16x32_bf16(a[mt], b, acc1[mt][nt], 0, 0, 0);
            }
        }
        __syncthreads();   // prior fc2 reads of Hs complete (WAR)
        #pragma unroll
        for (int nt = 0; nt < 3; ++nt) {
            int colb = wv * 48 + nt * 16 + lr;           // 0..191 within chunk
            float bias = f1b[hc * 192 + colb];
            #pragma unroll
            for (int mt = 0; mt < 4; ++mt) {
                #pragma unroll
                for (int reg = 0; reg < 4; ++reg) {
                    float v = acc1[mt][nt][reg] + bias;
                    Hs[(mt * 16 + q4 + reg) * 200 + colb] = f2bf(gelu_f(v));
                }
            }
        }
        __syncthreads();   // Hs visible to all waves (RAW)
        // ---- fc2 accumulate over this chunk's 192 hiddens ----
        for (int ks = 0; ks < 6; ++ks) {
            int k0 = ks * 32 + lk;
            short8 a[4];
            #pragma unroll
            for (int mt = 0; mt < 4; ++mt)
                a[mt] = *(const short8*)&Hs[(mt * 16 + lr) * 200 + k0];
            #pragma unroll
            for (int nt = 0; nt < 3; ++nt) {
                int c = wv * 48 + nt * 16 + lr;
                short8 b = *(const short8*)&w2t[c * 768 + hc * 192 + k0];
                #pragma unroll
                for (int mt = 0; mt < 4; ++mt)
                    acc2[mt][nt] = __builtin_amdgcn_mfma_f32_16x16x32_bf16(a[mt], b, acc2[mt][nt], 0, 0, 0);
            }
        }
    }
    #pragma unroll
    for (int nt = 0; nt < 3; ++nt) {
        int c = wv * 48 + nt * 16 + lr;
        float bias = f2b[c];
        #pragma unroll
        for (int mt = 0; mt < 4; ++mt) {
            #pragma unroll
            for (int reg = 0; reg < 4; ++reg) {
                size_t off = (size_t)(m0 + mt * 16 + q4 + reg) * CC + c;
                out[off] = out[off] + acc2[mt][nt][reg] + bias;
            }
        }
    }
}

extern "C" void kernel_launch(void* const* d_in, const int* in_sizes, int n_in,
                              void* d_out, int out_size, void* d_ws, size_t ws_size,
                              hipStream_t stream) {
    (void)in_sizes; (void)n_in; (void)out_size; (void)ws_size;
    const float* x    = (const float*)d_in[0];
    const float* n1g  = (const float*)d_in[3];
    const float* n1b  = (const float*)d_in[4];
    const float* qkvw = (const float*)d_in[5];
    const float* qkvb = (const float*)d_in[6];
    const float* rpb  = (const float*)d_in[7];
    const float* pw   = (const float*)d_in[8];
    const float* pb   = (const float*)d_in[9];
    const float* n2g  = (const float*)d_in[10];
    const float* n2b  = (const float*)d_in[11];
    const float* f1w  = (const float*)d_in[12];
    const float* f1b  = (const float*)d_in[13];
    const float* f2w  = (const float*)d_in[14];
    const float* f2b  = (const float*)d_in[15];
    float* out = (float*)d_out;

    ushort* Qb  = (ushort*)d_ws;            // 12,582,912 bf16 each
    ushort* Kb  = Qb + 12582912;
    ushort* VTb = Kb + 12582912;
    ushort* Ob  = VTb + 12582912;
    short* WQT  = (short*)(Ob + 12582912);  // 110,592 bf16
    short* PWT  = WQT + 110592;             // 36,864 bf16
    short* W1T  = PWT + 36864;              // 147,456 bf16
    short* W2T  = W1T + 147456;             // 147,456 bf16

    cvt_kernel<<<576, 256, 0, stream>>>(qkvw, pw, f1w, f2w, WQT, PWT, W1T, W2T);
    qkv_kernel<<<1024, 256, 0, stream>>>(x, n1g, n1b, WQT, qkvb, Qb, Kb, VTb);
    attn_kernel<<<1536, 256, 0, stream>>>(Qb, Kb, VTb, rpb, Ob);
    proj_kernel<<<1024, 256, 0, stream>>>(Ob, PWT, pb, x, out);
    mlp_kernel<<<1024, 256, 0, stream>>>(n2g, n2b, W1T, f1b, W2T, f2b, out);
}